// Round 1
// baseline (258.219 us; speedup 1.0000x reference)
//
#include <hip/hip_runtime.h>
#include <math.h>

#define KTOP 20
#define R_MAX 2048
#define SPLIT 8

typedef float f4v __attribute__((ext_vector_type(4)));

// ---------------------------------------------------------------------------
// Kernel A: streaming pass. grid = B*SPLIT blocks x 256 threads.
// Each block copies R/SPLIT rows of x[b] -> out (nontemporal float4), computes
// per-row dot(q, row) and ||row||, writes sims/dn to workspace.
// 2x unrolled: two independent dwordx4 loads in flight per wave.
// ---------------------------------------------------------------------------
__global__ __launch_bounds__(256, 6) void stream_sims(
    const float* __restrict__ x,
    const int* __restrict__ qrels,
    float* __restrict__ out,
    float* __restrict__ sims,
    float* __restrict__ dns,
    int R)
{
    __shared__ float s_q[64];
    const int blk = blockIdx.x;
    const int b = blk >> 3;            // blk / SPLIT
    const int s = blk & (SPLIT - 1);
    const int t = threadIdx.x;
    const int qr = qrels[b];
    const long xbase = (long)b * R * 64;

    // normalized query row (redundant per split-block; 256B read, cheap)
    if (t < 64) {
        float v = x[xbase + (long)qr * 64 + t];
        float ss = v * v;
#pragma unroll
        for (int m = 1; m < 64; m <<= 1) ss += __shfl_xor(ss, m, 64);
        s_q[t] = v / fmaxf(sqrtf(ss), 1e-12f);
    }
    __syncthreads();

    const int grp = t >> 4, l16 = t & 15;   // 16 groups of 16 lanes
    const float4 q4 = *(const float4*)(s_q + l16 * 4);
    const int rpb = R / SPLIT;
    const int row0 = s * rpb;
    const long sbase = (long)b * R;

    // each group handles rows {row0+grp+32k, row0+grp+16+32k}
    for (int r = row0 + grp; r < row0 + rpb; r += 32) {
        const int rA = r, rB = r + 16;
        const long baseA = xbase + (long)rA * 64 + l16 * 4;
        const long baseB = xbase + (long)rB * 64 + l16 * 4;
        const float4 vA = *(const float4*)(x + baseA);
        const float4 vB = *(const float4*)(x + baseB);
        // out is write-only in this pass: nontemporal keeps x resident in L3
        __builtin_nontemporal_store(*(const f4v*)&vA, (f4v*)(out + baseA));
        __builtin_nontemporal_store(*(const f4v*)&vB, (f4v*)(out + baseB));

        float dotA = vA.x * q4.x + vA.y * q4.y + vA.z * q4.z + vA.w * q4.w;
        float ssA  = vA.x * vA.x + vA.y * vA.y + vA.z * vA.z + vA.w * vA.w;
        float dotB = vB.x * q4.x + vB.y * q4.y + vB.z * q4.z + vB.w * q4.w;
        float ssB  = vB.x * vB.x + vB.y * vB.y + vB.z * vB.z + vB.w * vB.w;
#pragma unroll
        for (int m = 1; m < 16; m <<= 1) {  // stays inside the 16-lane group
            dotA += __shfl_xor(dotA, m, 64);
            ssA  += __shfl_xor(ssA,  m, 64);
            dotB += __shfl_xor(dotB, m, 64);
            ssB  += __shfl_xor(ssB,  m, 64);
        }
        if (l16 == 0) {
            float dnA = fmaxf(sqrtf(ssA), 1e-12f);
            float dnB = fmaxf(sqrtf(ssB), 1e-12f);
            sims[sbase + rA] = (rA == qr) ? -1.0f : dotA / dnA;
            sims[sbase + rB] = (rB == qr) ? -1.0f : dotB / dnB;
            dns[sbase + rA] = dnA;
            dns[sbase + rB] = dnB;
        }
    }
}

// ---------------------------------------------------------------------------
// Kernel B: selection + weighting + mixed-row write. grid = B x 256 threads.
// Same selection / weighting / mix logic (and fp order) as the verified
// fused kernel; sims/dn come from the workspace.
// ---------------------------------------------------------------------------
__global__ __launch_bounds__(256) void select_mix(
    const float* __restrict__ x,
    const int* __restrict__ qrels,
    const float* __restrict__ thr_raw,
    const float* __restrict__ str_raw,
    const float* __restrict__ wscale_p,
    const float* __restrict__ temp_p,
    const float* __restrict__ sims,
    const float* __restrict__ dns,
    float* __restrict__ out,
    int R)
{
    __shared__ float s_sims[R_MAX];
    __shared__ int   s_cand[R_MAX];
    __shared__ int   s_ncand;
    __shared__ float s_topv[KTOP];
    __shared__ int   s_topi[KTOP];
    __shared__ float s_dnsel[KTOP];
    __shared__ float s_adj[KTOP];
    __shared__ float s_strength;

    const int b = blockIdx.x;
    const int t = threadIdx.x;
    const int qr = qrels[b];
    const float threshold = 1.0f / (1.0f + expf(-thr_raw[0]));
    const long sbase = (long)b * R;
    const long xbase = (long)b * R * 64;

    if (t == 0) s_ncand = 0;
    __syncthreads();

    // load sims into LDS + compact candidates (sim > threshold; self is -1)
    for (int i = t; i < R; i += 256) {
        float sv = sims[sbase + i];
        s_sims[i] = sv;
        if (sv > threshold) {
            int p = atomicAdd(&s_ncand, 1);
            s_cand[p] = i;
        }
    }
    __syncthreads();

    const int ncand = s_ncand;
    const int ksel = ncand < KTOP ? ncand : KTOP;

    // ---- selection (wave 0) ----
    if (t < 64) {
        float myv = 0.0f; int myi = 0;
        if (ncand > KTOP) {
            // register-resident iterative argmax; JAX tie-break (value desc, idx asc)
            float lv[32]; int li[32];
#pragma unroll
            for (int j = 0; j < 32; ++j) {
                int i = t + 64 * j;
                if (i < ncand) { li[j] = s_cand[i]; lv[j] = s_sims[li[j]]; }
                else           { li[j] = 0x7fffffff; lv[j] = -INFINITY; }
            }
            for (int k = 0; k < KTOP; ++k) {
                float bv = -INFINITY; int bi = 0x7fffffff;
#pragma unroll
                for (int j = 0; j < 32; ++j)
                    if (lv[j] > bv || (lv[j] == bv && li[j] < bi)) { bv = lv[j]; bi = li[j]; }
#pragma unroll
                for (int m = 1; m < 64; m <<= 1) {   // butterfly: all lanes get winner
                    float v2 = __shfl_xor(bv, m, 64);
                    int   i2 = __shfl_xor(bi, m, 64);
                    if (v2 > bv || (v2 == bv && i2 < bi)) { bv = v2; bi = i2; }
                }
#pragma unroll
                for (int j = 0; j < 32; ++j) if (li[j] == bi) lv[j] = -INFINITY;
                if (t == k) { myv = bv; myi = bi; }   // lane k keeps k-th winner
            }
        } else if (t < ksel) {
            // <=20 candidates: selected set IS candidate set (order-invariant math)
            myi = s_cand[t];
            myv = s_sims[myi];
        }
        if (t < ksel) {
            s_topv[t] = myv;
            s_topi[t] = myi;
            s_dnsel[t] = dns[sbase + myi];   // parallel dn prefetch (L2 hit)
        }
    }
    __syncthreads();

    // ---- scalar weighting on lane 0 (all selected entries valid) ----
    if (t == 0) {
        float strength = (1.0f / (1.0f + expf(-str_raw[0]))) * 0.2f;
        float temp = fminf(fmaxf(temp_p[0], 0.1f), 10.0f);
        float wsc  = wscale_p[0];
        if (ksel > 0) {
            float m = -INFINITY;
            for (int k = 0; k < ksel; ++k) m = fmaxf(m, s_topv[k] / temp);
            float w[KTOP]; float wsum = 0.0f;
            for (int k = 0; k < ksel; ++k) { w[k] = expf(s_topv[k] / temp - m); wsum += w[k]; }
            float adj[KTOP]; float asum = 0.0f;
            for (int k = 0; k < ksel; ++k) {
                float tv = s_topv[k];
                float sw = 1.0f / (1.0f + expf(-(tv - threshold) * 10.0f));
                float a  = (w[k] / wsum) * sw * (1.0f + wsc * tv);
                adj[k] = a; asum += a;
            }
            for (int k = 0; k < ksel; ++k)
                s_adj[k] = (adj[k] / (asum + 1e-8f)) / s_dnsel[k];
        }
        s_strength = strength;
    }
    __syncthreads();

    // ---- write mixed query row (64 lanes) ----
    if (t < 64 && ksel > 0) {
        const long qb = xbase + (long)qr * 64 + t;
        float qo = x[qb];
        float acc = 0.0f;
        for (int k = 0; k < ksel; ++k)
            acc += s_adj[k] * x[xbase + (long)s_topi[k] * 64 + t];
        float st = s_strength;
        out[qb] = (1.0f - st) * qo + st * acc;
        // ksel==0: streaming pass already wrote the original row -> matches ref
    }
}

// ---------------------------------------------------------------------------
// Fallback: previous verified fused kernel (used if workspace too small or
// R not a multiple of 256).
// ---------------------------------------------------------------------------
__global__ __launch_bounds__(1024) void fused_enhancer(
    const float* __restrict__ x,
    const int* __restrict__ qrels,
    const float* __restrict__ thr_raw,
    const float* __restrict__ str_raw,
    const float* __restrict__ wscale_p,
    const float* __restrict__ temp_p,
    float* __restrict__ out, int R)
{
    __shared__ float s_q[64];
    __shared__ float s_sims[R_MAX];
    __shared__ float s_dn[R_MAX];
    __shared__ int   s_cand[R_MAX];
    __shared__ int   s_ncand;
    __shared__ float s_topv[KTOP];
    __shared__ int   s_topi[KTOP];
    __shared__ float s_adj[KTOP];
    __shared__ float s_strength;

    const int b = blockIdx.x;
    const int t = threadIdx.x;
    const int qr = qrels[b];
    const float threshold = 1.0f / (1.0f + expf(-thr_raw[0]));

    if (t == 0) s_ncand = 0;

    if (t < 64) {
        float v = x[((long)b * R + qr) * 64 + t];
        float ss = v * v;
#pragma unroll
        for (int m = 1; m < 64; m <<= 1) ss += __shfl_xor(ss, m, 64);
        s_q[t] = v / fmaxf(sqrtf(ss), 1e-12f);
    }
    __syncthreads();

    const int grp = t >> 4, l16 = t & 15;
    const float4 q4 = *(const float4*)(s_q + l16 * 4);
    const long xbase = (long)b * R * 64;
    for (int row = grp; row < R; row += 64) {
        long base = xbase + (long)row * 64 + l16 * 4;
        const float4 v = *(const float4*)(x + base);
        *(float4*)(out + base) = v;
        float dot = v.x * q4.x + v.y * q4.y + v.z * q4.z + v.w * q4.w;
        float ss  = v.x * v.x + v.y * v.y + v.z * v.z + v.w * v.w;
#pragma unroll
        for (int m = 1; m < 16; m <<= 1) {
            dot += __shfl_xor(dot, m, 64);
            ss  += __shfl_xor(ss,  m, 64);
        }
        if (l16 == 0) {
            float dn  = fmaxf(sqrtf(ss), 1e-12f);
            float sim = (row == qr) ? -1.0f : dot / dn;
            s_sims[row] = sim;
            s_dn[row]   = dn;
            if (sim > threshold) {
                int p = atomicAdd(&s_ncand, 1);
                s_cand[p] = row;
            }
        }
    }
    __syncthreads();

    const int ncand = s_ncand;
    const int ksel = ncand < KTOP ? ncand : KTOP;

    if (t < 64) {
        if (ncand > KTOP) {
            float lv[32]; int li[32];
#pragma unroll
            for (int j = 0; j < 32; ++j) {
                int i = t + 64 * j;
                if (i < ncand) { li[j] = s_cand[i]; lv[j] = s_sims[li[j]]; }
                else           { li[j] = 0x7fffffff; lv[j] = -INFINITY; }
            }
            for (int k = 0; k < KTOP; ++k) {
                float bv = -INFINITY; int bi = 0x7fffffff;
#pragma unroll
                for (int j = 0; j < 32; ++j) {
                    if (lv[j] > bv || (lv[j] == bv && li[j] < bi)) { bv = lv[j]; bi = li[j]; }
                }
#pragma unroll
                for (int m = 1; m < 64; m <<= 1) {
                    float v2 = __shfl_xor(bv, m, 64);
                    int   i2 = __shfl_xor(bi, m, 64);
                    if (v2 > bv || (v2 == bv && i2 < bi)) { bv = v2; bi = i2; }
                }
#pragma unroll
                for (int j = 0; j < 32; ++j) if (li[j] == bi) lv[j] = -INFINITY;
                if (t == 0) { s_topv[k] = bv; s_topi[k] = bi; }
            }
        } else if (t == 0) {
            for (int k = 0; k < ksel; ++k) {
                int idx = s_cand[k];
                s_topi[k] = idx;
                s_topv[k] = s_sims[idx];
            }
        }
    }

    if (t == 0) {
        float strength = (1.0f / (1.0f + expf(-str_raw[0]))) * 0.2f;
        float temp = fminf(fmaxf(temp_p[0], 0.1f), 10.0f);
        float wsc  = wscale_p[0];
        if (ksel > 0) {
            float m = -INFINITY;
            for (int k = 0; k < ksel; ++k) m = fmaxf(m, s_topv[k] / temp);
            float w[KTOP]; float wsum = 0.0f;
            for (int k = 0; k < ksel; ++k) { w[k] = expf(s_topv[k] / temp - m); wsum += w[k]; }
            float adj[KTOP]; float asum = 0.0f;
            for (int k = 0; k < ksel; ++k) {
                float tv = s_topv[k];
                float sw = 1.0f / (1.0f + expf(-(tv - threshold) * 10.0f));
                float a  = (w[k] / wsum) * sw * (1.0f + wsc * tv);
                adj[k] = a; asum += a;
            }
            for (int k = 0; k < ksel; ++k)
                s_adj[k] = (adj[k] / (asum + 1e-8f)) / s_dn[s_topi[k]];
        }
        s_strength = strength;
    }
    __syncthreads();

    if (t < 64 && ksel > 0) {
        long qb = ((long)b * R + qr) * 64 + t;
        float qo = x[qb];
        float acc = 0.0f;
        for (int k = 0; k < ksel; ++k)
            acc += s_adj[k] * x[((long)b * R + s_topi[k]) * 64 + t];
        float st = s_strength;
        out[qb] = (1.0f - st) * qo + st * acc;
    }
}

extern "C" void kernel_launch(void* const* d_in, const int* in_sizes, int n_in,
                              void* d_out, int out_size, void* d_ws, size_t ws_size,
                              hipStream_t stream) {
    const float* x      = (const float*)d_in[0];
    const int*   qrels  = (const int*)d_in[1];
    const float* thr    = (const float*)d_in[2];
    const float* str    = (const float*)d_in[3];
    const float* wscale = (const float*)d_in[4];
    const float* temp   = (const float*)d_in[5];
    float* out = (float*)d_out;

    const int B = in_sizes[1];
    const int D = 64;
    const int R = in_sizes[0] / (B * D);
    (void)D;

    const size_t need = (size_t)B * R * 2 * sizeof(float);
    if (d_ws != nullptr && ws_size >= need && (R % (SPLIT * 32)) == 0 && R <= R_MAX) {
        float* sims = (float*)d_ws;
        float* dns  = sims + (size_t)B * R;
        stream_sims<<<B * SPLIT, 256, 0, stream>>>(x, qrels, out, sims, dns, R);
        select_mix<<<B, 256, 0, stream>>>(x, qrels, thr, str, wscale, temp,
                                          sims, dns, out, R);
    } else {
        fused_enhancer<<<B, 1024, 0, stream>>>(x, qrels, thr, str, wscale, temp, out, R);
    }
}

// Round 4
// 252.159 us; speedup vs baseline: 1.0240x; 1.0240x over previous
//
#include <hip/hip_runtime.h>
#include <math.h>

#define KTOP 20
#define R_MAX 2048
#define SPLIT 8
#define ST 66   // LDS row stride in floats: 64 data + 2 pad (rows are D=64 wide!)

// ---------------------------------------------------------------------------
// Kernel A: streaming pass. grid = B*SPLIT blocks x 256 threads (4 waves).
// Each wave owns 64 rows as two 32-row half-tiles (A/B):
//   burst-load 16x dwordx4 upfront (both half-tiles in registers),
//   stage A to LDS (+ float4 store to out), per-lane dot vs q-in-registers
//   (2 lanes per row, 16x ds_read_b64, ONE shfl_xor(32)), then same for B.
// Single LDS tile per wave: DS ops complete in wave issue order, so dot-A
// reads finish before stage-B writes touch the tile — no barrier needed.
// ---------------------------------------------------------------------------
static_assert(sizeof(float) * (4 * 32 * ST + 64) < 36 * 1024, "LDS budget");

__global__ __launch_bounds__(256, 3) void stream_sims(
    const float* __restrict__ x,
    const int* __restrict__ qrels,
    float* __restrict__ out,
    float* __restrict__ sims,
    float* __restrict__ dns,
    int R)
{
    __shared__ float s_q[64];
    __shared__ float s_tile[4][32 * ST];   // [wave][row*ST+col] ~33.8 KB

    const int blk = blockIdx.x;
    const int b = blk >> 3;            // blk / SPLIT
    const int s = blk & (SPLIT - 1);
    const int t = threadIdx.x;
    const int qr = qrels[b];
    const long xbase = (long)b * R * 64;
    const long sbase = (long)b * R;

    // normalized query row (wave 0; small, once per block)
    if (t < 64) {
        float v = x[xbase + (long)qr * 64 + t];
        float ss = v * v;
#pragma unroll
        for (int m = 1; m < 64; m <<= 1) ss += __shfl_xor(ss, m, 64);
        s_q[t] = v / fmaxf(sqrtf(ss), 1e-12f);
    }
    __syncthreads();

    const int wid = t >> 6, lane = t & 63;
    const int g4 = lane >> 4, l16 = lane & 15;   // load mapping: 4 rows x 16 lanes
    const int h = lane >> 5, l32 = lane & 31;    // dot mapping: 2 lanes per row

    // q half-row in registers (8 float4 = 32 VGPR)
    float4 q[8];
#pragma unroll
    for (int k = 0; k < 8; ++k) q[k] = *(const float4*)(s_q + h * 32 + k * 4);

    const int row0 = s * (R / SPLIT) + wid * 64;   // this wave's 64 rows
    const int rA0 = row0, rB0 = row0 + 32;

    float* lds = &s_tile[wid][0];

    // ---- burst loads: 16 dwordx4 in flight per wave ----
    float4 vA[8], vB[8];
#pragma unroll
    for (int j = 0; j < 8; ++j)
        vA[j] = *(const float4*)(x + xbase + (long)(rA0 + g4 + 4 * j) * 64 + l16 * 4);
#pragma unroll
    for (int j = 0; j < 8; ++j)
        vB[j] = *(const float4*)(x + xbase + (long)(rB0 + g4 + 4 * j) * 64 + l16 * 4);

    // ---- half-tile A: store out + stage LDS ----
#pragma unroll
    for (int j = 0; j < 8; ++j) {
        const int r = g4 + 4 * j;
        *(float4*)(out + xbase + (long)(rA0 + r) * 64 + l16 * 4) = vA[j];
        float* p = lds + r * ST + l16 * 4;          // row stride 66: no overflow
        *(float2*)(p)     = make_float2(vA[j].x, vA[j].y);
        *(float2*)(p + 2) = make_float2(vA[j].z, vA[j].w);
    }
    // ---- dot A: lane owns half of row rA0+l32 ----
    {
        float dot = 0.0f, ssv = 0.0f;
        const float* rp = lds + l32 * ST + h * 32;
#pragma unroll
        for (int k = 0; k < 16; ++k) {
            float2 rv = *(const float2*)(rp + 2 * k);
            const float* qf = (const float*)&q[k >> 1];
            float qa = qf[(2 * k) & 3], qb = qf[(2 * k + 1) & 3];
            dot += rv.x * qa + rv.y * qb;
            ssv += rv.x * rv.x + rv.y * rv.y;
        }
        dot += __shfl_xor(dot, 32, 64);
        ssv += __shfl_xor(ssv, 32, 64);
        if (h == 0) {
            const int row = rA0 + l32;
            float dn = fmaxf(sqrtf(ssv), 1e-12f);
            sims[sbase + row] = (row == qr) ? -1.0f : dot / dn;
            dns[sbase + row] = dn;
        }
    }

    // ---- half-tile B: store out + stage LDS (reuses the tile; DS in-order) ----
#pragma unroll
    for (int j = 0; j < 8; ++j) {
        const int r = g4 + 4 * j;
        *(float4*)(out + xbase + (long)(rB0 + r) * 64 + l16 * 4) = vB[j];
        float* p = lds + r * ST + l16 * 4;
        *(float2*)(p)     = make_float2(vB[j].x, vB[j].y);
        *(float2*)(p + 2) = make_float2(vB[j].z, vB[j].w);
    }
    // ---- dot B ----
    {
        float dot = 0.0f, ssv = 0.0f;
        const float* rp = lds + l32 * ST + h * 32;
#pragma unroll
        for (int k = 0; k < 16; ++k) {
            float2 rv = *(const float2*)(rp + 2 * k);
            const float* qf = (const float*)&q[k >> 1];
            float qa = qf[(2 * k) & 3], qb = qf[(2 * k + 1) & 3];
            dot += rv.x * qa + rv.y * qb;
            ssv += rv.x * rv.x + rv.y * rv.y;
        }
        dot += __shfl_xor(dot, 32, 64);
        ssv += __shfl_xor(ssv, 32, 64);
        if (h == 0) {
            const int row = rB0 + l32;
            float dn = fmaxf(sqrtf(ssv), 1e-12f);
            sims[sbase + row] = (row == qr) ? -1.0f : dot / dn;
            dns[sbase + row] = dn;
        }
    }
}

// ---------------------------------------------------------------------------
// Kernel B: selection + weighting + mixed-row write. grid = B x 256 threads.
// Verified logic (fp order identical to the round-1 passing kernel).
// ---------------------------------------------------------------------------
__global__ __launch_bounds__(256) void select_mix(
    const float* __restrict__ x,
    const int* __restrict__ qrels,
    const float* __restrict__ thr_raw,
    const float* __restrict__ str_raw,
    const float* __restrict__ wscale_p,
    const float* __restrict__ temp_p,
    const float* __restrict__ sims,
    const float* __restrict__ dns,
    float* __restrict__ out,
    int R)
{
    __shared__ float s_sims[R_MAX];
    __shared__ int   s_cand[R_MAX];
    __shared__ int   s_ncand;
    __shared__ float s_topv[KTOP];
    __shared__ int   s_topi[KTOP];
    __shared__ float s_dnsel[KTOP];
    __shared__ float s_adj[KTOP];
    __shared__ float s_strength;

    const int b = blockIdx.x;
    const int t = threadIdx.x;
    const int qr = qrels[b];
    const float threshold = 1.0f / (1.0f + expf(-thr_raw[0]));
    const long sbase = (long)b * R;
    const long xbase = (long)b * R * 64;

    if (t == 0) s_ncand = 0;
    __syncthreads();

    for (int i = t; i < R; i += 256) {
        float sv = sims[sbase + i];
        s_sims[i] = sv;
        if (sv > threshold) {
            int p = atomicAdd(&s_ncand, 1);
            s_cand[p] = i;
        }
    }
    __syncthreads();

    const int ncand = s_ncand;
    const int ksel = ncand < KTOP ? ncand : KTOP;

    if (t < 64) {
        float myv = 0.0f; int myi = 0;
        if (ncand > KTOP) {
            float lv[32]; int li[32];
#pragma unroll
            for (int j = 0; j < 32; ++j) {
                int i = t + 64 * j;
                if (i < ncand) { li[j] = s_cand[i]; lv[j] = s_sims[li[j]]; }
                else           { li[j] = 0x7fffffff; lv[j] = -INFINITY; }
            }
            for (int k = 0; k < KTOP; ++k) {
                float bv = -INFINITY; int bi = 0x7fffffff;
#pragma unroll
                for (int j = 0; j < 32; ++j)
                    if (lv[j] > bv || (lv[j] == bv && li[j] < bi)) { bv = lv[j]; bi = li[j]; }
#pragma unroll
                for (int m = 1; m < 64; m <<= 1) {
                    float v2 = __shfl_xor(bv, m, 64);
                    int   i2 = __shfl_xor(bi, m, 64);
                    if (v2 > bv || (v2 == bv && i2 < bi)) { bv = v2; bi = i2; }
                }
#pragma unroll
                for (int j = 0; j < 32; ++j) if (li[j] == bi) lv[j] = -INFINITY;
                if (t == k) { myv = bv; myi = bi; }
            }
        } else if (t < ksel) {
            myi = s_cand[t];
            myv = s_sims[myi];
        }
        if (t < ksel) {
            s_topv[t] = myv;
            s_topi[t] = myi;
            s_dnsel[t] = dns[sbase + myi];
        }
    }
    __syncthreads();

    if (t == 0) {
        float strength = (1.0f / (1.0f + expf(-str_raw[0]))) * 0.2f;
        float temp = fminf(fmaxf(temp_p[0], 0.1f), 10.0f);
        float wsc  = wscale_p[0];
        if (ksel > 0) {
            float m = -INFINITY;
            for (int k = 0; k < ksel; ++k) m = fmaxf(m, s_topv[k] / temp);
            float w[KTOP]; float wsum = 0.0f;
            for (int k = 0; k < ksel; ++k) { w[k] = expf(s_topv[k] / temp - m); wsum += w[k]; }
            float adj[KTOP]; float asum = 0.0f;
            for (int k = 0; k < ksel; ++k) {
                float tv = s_topv[k];
                float sw = 1.0f / (1.0f + expf(-(tv - threshold) * 10.0f));
                float a  = (w[k] / wsum) * sw * (1.0f + wsc * tv);
                adj[k] = a; asum += a;
            }
            for (int k = 0; k < ksel; ++k)
                s_adj[k] = (adj[k] / (asum + 1e-8f)) / s_dnsel[k];
        }
        s_strength = strength;
    }
    __syncthreads();

    if (t < 64 && ksel > 0) {
        const long qb = xbase + (long)qr * 64 + t;
        float qo = x[qb];
        float acc = 0.0f;
        for (int k = 0; k < ksel; ++k)
            acc += s_adj[k] * x[xbase + (long)s_topi[k] * 64 + t];
        float st = s_strength;
        out[qb] = (1.0f - st) * qo + st * acc;
    }
}

// ---------------------------------------------------------------------------
// Fallback: original verified fused kernel (odd shapes / no workspace).
// ---------------------------------------------------------------------------
__global__ __launch_bounds__(1024) void fused_enhancer(
    const float* __restrict__ x,
    const int* __restrict__ qrels,
    const float* __restrict__ thr_raw,
    const float* __restrict__ str_raw,
    const float* __restrict__ wscale_p,
    const float* __restrict__ temp_p,
    float* __restrict__ out, int R)
{
    __shared__ float s_q[64];
    __shared__ float s_sims[R_MAX];
    __shared__ float s_dn[R_MAX];
    __shared__ int   s_cand[R_MAX];
    __shared__ int   s_ncand;
    __shared__ float s_topv[KTOP];
    __shared__ int   s_topi[KTOP];
    __shared__ float s_adj[KTOP];
    __shared__ float s_strength;

    const int b = blockIdx.x;
    const int t = threadIdx.x;
    const int qr = qrels[b];
    const float threshold = 1.0f / (1.0f + expf(-thr_raw[0]));

    if (t == 0) s_ncand = 0;

    if (t < 64) {
        float v = x[((long)b * R + qr) * 64 + t];
        float ss = v * v;
#pragma unroll
        for (int m = 1; m < 64; m <<= 1) ss += __shfl_xor(ss, m, 64);
        s_q[t] = v / fmaxf(sqrtf(ss), 1e-12f);
    }
    __syncthreads();

    const int grp = t >> 4, l16 = t & 15;
    const float4 q4 = *(const float4*)(s_q + l16 * 4);
    const long xbase = (long)b * R * 64;
    for (int row = grp; row < R; row += 64) {
        long base = xbase + (long)row * 64 + l16 * 4;
        const float4 v = *(const float4*)(x + base);
        *(float4*)(out + base) = v;
        float dot = v.x * q4.x + v.y * q4.y + v.z * q4.z + v.w * q4.w;
        float ss  = v.x * v.x + v.y * v.y + v.z * v.z + v.w * v.w;
#pragma unroll
        for (int m = 1; m < 16; m <<= 1) {
            dot += __shfl_xor(dot, m, 64);
            ss  += __shfl_xor(ss,  m, 64);
        }
        if (l16 == 0) {
            float dn  = fmaxf(sqrtf(ss), 1e-12f);
            float sim = (row == qr) ? -1.0f : dot / dn;
            s_sims[row] = sim;
            s_dn[row]   = dn;
            if (sim > threshold) {
                int p = atomicAdd(&s_ncand, 1);
                s_cand[p] = row;
            }
        }
    }
    __syncthreads();

    const int ncand = s_ncand;
    const int ksel = ncand < KTOP ? ncand : KTOP;

    if (t < 64) {
        if (ncand > KTOP) {
            float lv[32]; int li[32];
#pragma unroll
            for (int j = 0; j < 32; ++j) {
                int i = t + 64 * j;
                if (i < ncand) { li[j] = s_cand[i]; lv[j] = s_sims[li[j]]; }
                else           { li[j] = 0x7fffffff; lv[j] = -INFINITY; }
            }
            for (int k = 0; k < KTOP; ++k) {
                float bv = -INFINITY; int bi = 0x7fffffff;
#pragma unroll
                for (int j = 0; j < 32; ++j) {
                    if (lv[j] > bv || (lv[j] == bv && li[j] < bi)) { bv = lv[j]; bi = li[j]; }
                }
#pragma unroll
                for (int m = 1; m < 64; m <<= 1) {
                    float v2 = __shfl_xor(bv, m, 64);
                    int   i2 = __shfl_xor(bi, m, 64);
                    if (v2 > bv || (v2 == bv && i2 < bi)) { bv = v2; bi = i2; }
                }
#pragma unroll
                for (int j = 0; j < 32; ++j) if (li[j] == bi) lv[j] = -INFINITY;
                if (t == 0) { s_topv[k] = bv; s_topi[k] = bi; }
            }
        } else if (t == 0) {
            for (int k = 0; k < ksel; ++k) {
                int idx = s_cand[k];
                s_topi[k] = idx;
                s_topv[k] = s_sims[idx];
            }
        }
    }

    if (t == 0) {
        float strength = (1.0f / (1.0f + expf(-str_raw[0]))) * 0.2f;
        float temp = fminf(fmaxf(temp_p[0], 0.1f), 10.0f);
        float wsc  = wscale_p[0];
        if (ksel > 0) {
            float m = -INFINITY;
            for (int k = 0; k < ksel; ++k) m = fmaxf(m, s_topv[k] / temp);
            float w[KTOP]; float wsum = 0.0f;
            for (int k = 0; k < ksel; ++k) { w[k] = expf(s_topv[k] / temp - m); wsum += w[k]; }
            float adj[KTOP]; float asum = 0.0f;
            for (int k = 0; k < ksel; ++k) {
                float tv = s_topv[k];
                float sw = 1.0f / (1.0f + expf(-(tv - threshold) * 10.0f));
                float a  = (w[k] / wsum) * sw * (1.0f + wsc * tv);
                adj[k] = a; asum += a;
            }
            for (int k = 0; k < ksel; ++k)
                s_adj[k] = (adj[k] / (asum + 1e-8f)) / s_dn[s_topi[k]];
        }
        s_strength = strength;
    }
    __syncthreads();

    if (t < 64 && ksel > 0) {
        long qb = ((long)b * R + qr) * 64 + t;
        float qo = x[qb];
        float acc = 0.0f;
        for (int k = 0; k < ksel; ++k)
            acc += s_adj[k] * x[((long)b * R + s_topi[k]) * 64 + t];
        float st = s_strength;
        out[qb] = (1.0f - st) * qo + st * acc;
    }
}

extern "C" void kernel_launch(void* const* d_in, const int* in_sizes, int n_in,
                              void* d_out, int out_size, void* d_ws, size_t ws_size,
                              hipStream_t stream) {
    const float* x      = (const float*)d_in[0];
    const int*   qrels  = (const int*)d_in[1];
    const float* thr    = (const float*)d_in[2];
    const float* str    = (const float*)d_in[3];
    const float* wscale = (const float*)d_in[4];
    const float* temp   = (const float*)d_in[5];
    float* out = (float*)d_out;

    const int B = in_sizes[1];
    const int D = 64;
    const int R = in_sizes[0] / (B * D);
    (void)D;

    const size_t need = (size_t)B * R * 2 * sizeof(float);
    // new path needs R divisible by SPLIT*256 (each block = 4 waves x 64 rows)
    if (d_ws != nullptr && ws_size >= need && (R % (SPLIT * 256)) == 0 && R <= R_MAX) {
        float* sims = (float*)d_ws;
        float* dns  = sims + (size_t)B * R;
        stream_sims<<<B * SPLIT, 256, 0, stream>>>(x, qrels, out, sims, dns, R);
        select_mix<<<B, 256, 0, stream>>>(x, qrels, thr, str, wscale, temp,
                                          sims, dns, out, R);
    } else {
        fused_enhancer<<<B, 1024, 0, stream>>>(x, qrels, thr, str, wscale, temp, out, R);
    }
}